// Round 10
// baseline (850.671 us; speedup 1.0000x reference)
//
#include <hip/hip_runtime.h>
#include <cstdint>

#define T_STEPS 128
#define BATCH   1024
#define D_INPUT 96
#define H_DIM   128
#define NWIN    163   // 121 full 7-frame windows + 6 prefix partials + 36 clipped partials
#define BD      (BATCH * D_INPUT)   // 98304 floats per time frame

// (t, s) -> widx, or -1 when the reference window is empty (cur1 == +0)
__device__ __forceinline__ int widx_for(int t, int s) {
    if (t >= 49) return t - 49 + 7 * s;                 // slide regime: full windows
    if (s == 0)  return 121 + min(5, t);                // [0, min(5,t)]
    const int st = 7 * s - 1;
    if (t < st) return -1;
    const int len = min(7, t - st + 1);
    return (len == 7) ? st : (127 + (s - 1) * 6 + (len - 1));
}

// ---------------------------------------------------------------------------
// kT: one-shot weight reshapes.
//   blocks 0..47  : Win (128x96)  -> WinT (96x128)
//   blocks 48..111: Wh0 (128x128) -> Wh0P packed per (j, lane=i-pair l):
//     Wh0P[(j*64+l)*4 + {0,1,2,3}] = { Wh0[2l][2j], Wh0[2l+1][2j],
//                                      Wh0[2l][2j+1], Wh0[2l+1][2j+1] }
// ---------------------------------------------------------------------------
__global__ __launch_bounds__(256) void kT_wint(const float* __restrict__ Win,
                                               const float* __restrict__ Wh0,
                                               float* __restrict__ WinT,
                                               float* __restrict__ Wh0P) {
    const int tid = threadIdx.x;
    if (blockIdx.x < 48) {
        const int e = blockIdx.x * 256 + tid;           // < 128*96
        const int h = e / D_INPUT, d = e % D_INPUT;
        WinT[d * H_DIM + h] = Win[e];
    } else {
        const int e = (blockIdx.x - 48) * 256 + tid;    // < 64*64*4 = 16384
        const int f = e & 3, l = (e >> 2) & 63, j = e >> 8;
        const int i = 2 * l + (f & 1);
        const int h = 2 * j + (f >> 1);
        Wh0P[e] = Wh0[i * H_DIM + h];
    }
}

// ---------------------------------------------------------------------------
// kA0: one streaming pass over x. Thread <-> (b,d); 7-frame ring in registers
// (t-loop fully unrolled -> all ring indices compile-time -> no scratch).
// Emits every window sum with the EXACT ascending-frame __fadd_rn chain.
// UNCHANGED.
// ---------------------------------------------------------------------------
__global__ __launch_bounds__(256) void kA0_winsum(const float* __restrict__ x,
                                                  float* __restrict__ WS) {
    const int flat = blockIdx.x * 256 + threadIdx.x;    // b*96 + d
    float* wsp = WS + flat;
    float r[7];
#pragma unroll
    for (int t = 0; t < T_STEPS; ++t) {
        r[t % 7] = x[(size_t)t * BD + flat];
        if (t <= 5) {                                   // s0 prefix, len = t+1
            float s = r[0];
#pragma unroll
            for (int k = 1; k <= t; ++k) s = __fadd_rn(s, r[k % 7]);
            wsp[(size_t)(121 + t) * BD] = s;
        }
        if (t >= 6 && t <= 126) {                       // full window w = t-6
            const int w = t - 6;
            float s = r[w % 7];
#pragma unroll
            for (int k = 1; k < 7; ++k) s = __fadd_rn(s, r[(w + k) % 7]);
            wsp[(size_t)w * BD] = s;
        }
        if (t >= 6 && t <= 46) {                        // grow partial (<=1 per t)
            const int sv = (t + 1) / 7;
            if (sv >= 1 && 7 * sv >= t - 4 && 7 * sv <= t + 1) {
                const int start = 7 * sv - 1;
                const int len = t - start + 1;          // 1..6 by construction
                float s = r[start % 7];
#pragma unroll
                for (int k = 1; k < len; ++k) s = __fadd_rn(s, r[(start + k) % 7]);
                wsp[(size_t)(127 + (sv - 1) * 6 + (len - 1)) * BD] = s;
            }
        }
    }
}

// ---------------------------------------------------------------------------
// kA1 (r6 version, verified): 64-b tile, lane = (h-quad q, b-octet).
// CUR1 bit-identical (ascending-d single-acc fma chain). UNCHANGED.
// ---------------------------------------------------------------------------
__global__ __launch_bounds__(256) void kA_wincur(const float* __restrict__ WS,
                                                 const float* __restrict__ WinT,
                                                 float* __restrict__ CUR1) {
    __shared__ float xs[D_INPUT * 64];                  // 24 KB, xs[d*64 + (bq^(d&24))]
    __shared__ float wq[D_INPUT * H_DIM];               // 48 KB, pair-split per row
    const int widx = blockIdx.x;
    const int b0   = blockIdx.y * 64;
    const int tid  = threadIdx.x;

    {
        const float2* WinT2 = (const float2*)WinT;
        for (int e2 = tid; e2 < D_INPUT * 64; e2 += 256) {
            const int p = e2 & 63, d = e2 >> 6;
            *(float2*)&wq[d * 128 + ((p & 1) << 6) + ((p >> 1) << 1)] = WinT2[e2];
        }
    }
    for (int e = tid; e < D_INPUT * 64; e += 256) {
        const int d = e % 96, bq = e / 96;
        xs[d * 64 + (bq ^ (d & 24))] =
            WS[(size_t)widx * BD + (size_t)(b0 + bq) * 96 + d];
    }
    __syncthreads();

    const int q  = tid & 31;                            // h-quad (4 h's)
    const int g  = (tid >> 5) & 1;
    const int w  = tid >> 6;
    const int ob = (w << 1) | g;                        // b-octet 0..7

    float acc[8][4];
#pragma unroll
    for (int r = 0; r < 8; ++r)
#pragma unroll
        for (int hh = 0; hh < 4; ++hh) acc[r][hh] = 0.f;

#pragma unroll 4
    for (int d = 0; d < D_INPUT; ++d) {
        const float2 wp0 = *(const float2*)&wq[d * 128 + 2 * q];       // h=4q,4q+1
        const float2 wp1 = *(const float2*)&wq[d * 128 + 64 + 2 * q];  // h=4q+2,4q+3
        const int xb = d * 64 + ((ob * 8) ^ (d & 24));
        const float4 xv0 = *(const float4*)&xs[xb];
        const float4 xv1 = *(const float4*)&xs[xb + 4];
        const float xv[8] = {xv0.x,xv0.y,xv0.z,xv0.w, xv1.x,xv1.y,xv1.z,xv1.w};
#pragma unroll
        for (int r = 0; r < 8; ++r) {
            acc[r][0] = __fmaf_rn(xv[r], wp0.x, acc[r][0]);
            acc[r][1] = __fmaf_rn(xv[r], wp0.y, acc[r][1]);
            acc[r][2] = __fmaf_rn(xv[r], wp1.x, acc[r][2]);
            acc[r][3] = __fmaf_rn(xv[r], wp1.y, acc[r][3]);
        }
    }
    float* op = CUR1 + ((size_t)widx * BATCH + b0 + ob * 8) * H_DIM + 4 * q;
#pragma unroll
    for (int r = 0; r < 8; ++r) {
        float4 o; o.x = acc[r][0]; o.y = acc[r][1]; o.z = acc[r][2]; o.w = acc[r][3];
        *(float4*)(op + (size_t)r * H_DIM) = o;
    }
}

// ---------------------------------------------------------------------------
// kB (round-10): r9 body verbatim; ONLY the launch bound changes.
// r9 evidence: (1024,8) forced VGPR cap to 32 (counter) -> 1.27 GB scratch
// spill per dispatch (WRITE 858 MB / FETCH 386 MB) — yet dur still improved
// 597->585 µs because occupancy hit 66% (32 waves/CU). So the 1024-thread
// shared-table shape is right; only the register cap is wrong.
// (1024,4) = VGPR cap 128: the body naturally allocates ~60 VGPR (r8
// counter at an unconstrained cap), and 60 <= 64 still admits 8 waves/SIMD;
// LDS (one 64 KB table per 16-wave block, 2 blocks/CU) stays the occupancy
// limiter at 32 waves/CU. Spill tripwire: WRITE_SIZE must return to ~1 KB.
// Readlane spike path, LDS weights, fma chain/operands: bit-identical.
// ---------------------------------------------------------------------------
__global__ __launch_bounds__(1024, 4) void kB_snn(const float* __restrict__ CUR1,
                                                  const float* __restrict__ Wh0P,
                                                  const float* __restrict__ Wout,
                                                  const float* __restrict__ vxp,
                                                  const float* __restrict__ vyp,
                                                  float* __restrict__ out) {
    __shared__ float4 lw[64 * 64];                     // 64 KB: lw[j*64 + lane]
    const int tid  = threadIdx.x;

    // stage weight table once (coalesced float4, 4 per thread)
    {
        const float4* src = (const float4*)Wh0P;
        for (int e = tid; e < 4096; e += 1024) lw[e] = src[e];
    }
    __syncthreads();

    const int w    = tid >> 6, lane = tid & 63;        // w in [0,16)
    const int t    = blockIdx.y;
    const int i0   = lane << 1;                 // mem1: h-pair; cur2: i-pair
    const int b0   = (blockIdx.x << 7) + (w << 3);   // 8 consecutive b per wave
    const float vx = vxp[0], vy = vyp[0];
    const float wex0 = Wout[i0],         wex1 = Wout[i0 + 1];
    const float wey0 = Wout[H_DIM + i0], wey1 = Wout[H_DIM + i0 + 1];

    float m1a[8], m1b[8];                       // h = 2*lane / 2*lane+1, x 8 b
    bool  s1a[8], s1b[8];
    float m2[8][2], po0[8], po1[8];
    bool  s2[8][2];
#pragma unroll
    for (int k = 0; k < 8; ++k) {
        m1a[k] = 0.f; m1b[k] = 0.f; s1a[k] = false; s1b[k] = false;
        m2[k][0] = 0.f; m2[k][1] = 0.f; s2[k][0] = false; s2[k][1] = false;
        po0[k] = 0.f; po1[k] = 0.f;
    }

#pragma unroll 1
    for (int s = 0; s < 7; ++s) {
        // ---- load cur1 for this step (coalesced float2 per b) --------------
        const int wi = widx_for(t, s);
        float c1a[8], c1b[8];
#pragma unroll
        for (int k = 0; k < 8; ++k) {
            c1a[k] = 0.f; c1b[k] = 0.f;
            if (wi >= 0) {
                const float2 v = *(const float2*)
                    &CUR1[((size_t)wi * BATCH + b0 + k) * H_DIM + i0];
                c1a[k] = v.x; c1b[k] = v.y;
            }
        }

        // ---- mem1 update + pack spike bits (exact values) ------------------
        uint32_t mk = 0u;                       // bits 0..7 = se(h=2*lane), 8..15 = so
#pragma unroll
        for (int k = 0; k < 8; ++k) {
            m1a[k] = s1a[k] ? 0.f : __fadd_rn(__fmul_rn(0.9f, m1a[k]), c1a[k]);
            m1b[k] = s1b[k] ? 0.f : __fadd_rn(__fmul_rn(0.9f, m1b[k]), c1b[k]);
            s1a[k] = m1a[k] > 0.5f; s1b[k] = m1b[k] > 0.5f;
            mk |= (s1a[k] ? (1u << k) : 0u) | (s1b[k] ? (0x100u << k) : 0u);
        }

        // ---- dense cur2: ascending h; spikes via readlane, weights via LDS -
        float c2[8][2];
#pragma unroll
        for (int k = 0; k < 8; ++k) { c2[k][0] = 0.f; c2[k][1] = 0.f; }

#pragma unroll 4
        for (int j = 0; j < 64; ++j) {
            const float4 wv = lw[j * 64 + lane];                 // ds_read_b128
            const uint32_t M = (uint32_t)__builtin_amdgcn_readlane((int)mk, j);
#pragma unroll
            for (int k = 0; k < 8; ++k) {
                const float se = (M & (1u     << k)) ? 1.0f : 0.0f;  // uniform -> SGPR
                const float so = (M & (0x100u << k)) ? 1.0f : 0.0f;
                c2[k][0] = __fmaf_rn(se, wv.x, c2[k][0]);   // h = 2j,   i = i0
                c2[k][1] = __fmaf_rn(se, wv.y, c2[k][1]);   // h = 2j,   i = i0+1
                c2[k][0] = __fmaf_rn(so, wv.z, c2[k][0]);   // h = 2j+1, i = i0
                c2[k][1] = __fmaf_rn(so, wv.w, c2[k][1]);   // h = 2j+1, i = i0+1
            }
        }

        // ---- mem2 + spikes (exact) and linear output tail (relaxed) --------
#pragma unroll
        for (int k = 0; k < 8; ++k) {
            m2[k][0] = s2[k][0] ? 0.f : __fadd_rn(__fmul_rn(0.9f, m2[k][0]), c2[k][0]);
            m2[k][1] = s2[k][1] ? 0.f : __fadd_rn(__fmul_rn(0.9f, m2[k][1]), c2[k][1]);
            s2[k][0] = m2[k][0] > 0.5f; s2[k][1] = m2[k][1] > 0.5f;
            const float p0 = (s2[k][0] ? wex0 : 0.f) + (s2[k][1] ? wex1 : 0.f);
            const float p1 = (s2[k][0] ? wey0 : 0.f) + (s2[k][1] ? wey1 : 0.f);
            po0[k] = __fmaf_rn(0.9f, po0[k], p0);   // mem_out linear: order-safe
            po1[k] = __fmaf_rn(0.9f, po1[k], p1);
        }
    }

    // ---- reduce per-lane (2-i) partials over 64 lanes (128 i), write -------
#pragma unroll
    for (int k = 0; k < 8; ++k) {
        float r0 = po0[k], r1 = po1[k];
#pragma unroll
        for (int off = 32; off > 0; off >>= 1) {
            r0 += __shfl_xor(r0, off);
            r1 += __shfl_xor(r1, off);
        }
        if (lane == 0) {
            float2 o;
            o.x = __fmul_rn(r0, vx);
            o.y = __fmul_rn(r1, vy);
            *(float2*)(out + ((size_t)t * BATCH + b0 + k) * 2) = o;
        }
    }
}

// ---------------------------------------------------------------------------
extern "C" void kernel_launch(void* const* d_in, const int* in_sizes, int n_in,
                              void* d_out, int out_size, void* d_ws, size_t ws_size,
                              hipStream_t stream) {
    const float* x    = (const float*)d_in[0];   // (128,1024,96)
    const float* Win  = (const float*)d_in[1];   // (128,96)
    const float* Wh0  = (const float*)d_in[2];   // (128,128)
    const float* Wout = (const float*)d_in[3];   // (2,128)
    const float* vx   = (const float*)d_in[4];   // (1,)
    const float* vy   = (const float*)d_in[5];   // (1,)
    float* out  = (float*)d_out;                 // (128,1024,2)

    // workspace: CUR1 (85.5 MB) | WS (64.1 MB) | WinT (48 KB) | Wh0P (64 KB)
    float* CUR1 = (float*)d_ws;
    float* WS   = CUR1 + (size_t)NWIN * BATCH * H_DIM;
    float* WinT = WS   + (size_t)NWIN * BATCH * D_INPUT;
    float* Wh0P = WinT + (size_t)D_INPUT * H_DIM;

    kT_wint   <<<dim3(112),                  dim3(256), 0, stream>>>(Win, Wh0, WinT, Wh0P);
    kA0_winsum<<<dim3(BD / 256),             dim3(256), 0, stream>>>(x, WS);
    kA_wincur <<<dim3(NWIN, BATCH / 64),     dim3(256), 0, stream>>>(WS, WinT, CUR1);
    kB_snn    <<<dim3(BATCH / 128, T_STEPS), dim3(1024), 0, stream>>>(CUR1, Wh0P, Wout, vx, vy, out);
}

// Round 11
// 778.469 us; speedup vs baseline: 1.0927x; 1.0927x over previous
//
#include <hip/hip_runtime.h>
#include <cstdint>

#define T_STEPS 128
#define BATCH   1024
#define D_INPUT 96
#define H_DIM   128
#define NWIN    163   // 121 full 7-frame windows + 6 prefix partials + 36 clipped partials
#define BD      (BATCH * D_INPUT)   // 98304 floats per time frame

// (t, s) -> widx, or -1 when the reference window is empty (cur1 == +0)
__device__ __forceinline__ int widx_for(int t, int s) {
    if (t >= 49) return t - 49 + 7 * s;                 // slide regime: full windows
    if (s == 0)  return 121 + min(5, t);                // [0, min(5,t)]
    const int st = 7 * s - 1;
    if (t < st) return -1;
    const int len = min(7, t - st + 1);
    return (len == 7) ? st : (127 + (s - 1) * 6 + (len - 1));
}

// ---------------------------------------------------------------------------
// kT (r5 version): one-shot weight reshapes.
//   blocks 0..47  : Win (128x96)  -> WinT (96x128)
//   blocks 48..111: Wh0 (128x128) -> Wh0Q packed per (j, i-quad q):
//     Wh0Q[((j*32+q)*2+p)*4 + r] = Wh0[(4q+r)*128 + (2j+p)]
//   so kB's lane (i-quad q) fetches w[h=2j][i=4q..4q+3] and w[h=2j+1][...]
//   as TWO coalesced float4 loads per j from the L2-resident 64 KB table.
// ---------------------------------------------------------------------------
__global__ __launch_bounds__(256) void kT_wint(const float* __restrict__ Win,
                                               const float* __restrict__ Wh0,
                                               float* __restrict__ WinT,
                                               float* __restrict__ Wh0Q) {
    const int tid = threadIdx.x;
    if (blockIdx.x < 48) {
        const int e = blockIdx.x * 256 + tid;           // < 128*96
        const int h = e / D_INPUT, d = e % D_INPUT;
        WinT[d * H_DIM + h] = Win[e];
    } else {
        const int e = (blockIdx.x - 48) * 256 + tid;    // < 64*32*2*4 = 16384
        const int r = e & 3, p = (e >> 2) & 1, q = (e >> 3) & 31, j = e >> 8;
        Wh0Q[e] = Wh0[(4 * q + r) * H_DIM + (2 * j + p)];
    }
}

// ---------------------------------------------------------------------------
// kA0: one streaming pass over x. Thread <-> (b,d); 7-frame ring in registers
// (t-loop fully unrolled -> all ring indices compile-time -> no scratch).
// Emits every window sum with the EXACT ascending-frame __fadd_rn chain.
// UNCHANGED.
// ---------------------------------------------------------------------------
__global__ __launch_bounds__(256) void kA0_winsum(const float* __restrict__ x,
                                                  float* __restrict__ WS) {
    const int flat = blockIdx.x * 256 + threadIdx.x;    // b*96 + d
    float* wsp = WS + flat;
    float r[7];
#pragma unroll
    for (int t = 0; t < T_STEPS; ++t) {
        r[t % 7] = x[(size_t)t * BD + flat];
        if (t <= 5) {                                   // s0 prefix, len = t+1
            float s = r[0];
#pragma unroll
            for (int k = 1; k <= t; ++k) s = __fadd_rn(s, r[k % 7]);
            wsp[(size_t)(121 + t) * BD] = s;
        }
        if (t >= 6 && t <= 126) {                       // full window w = t-6
            const int w = t - 6;
            float s = r[w % 7];
#pragma unroll
            for (int k = 1; k < 7; ++k) s = __fadd_rn(s, r[(w + k) % 7]);
            wsp[(size_t)w * BD] = s;
        }
        if (t >= 6 && t <= 46) {                        // grow partial (<=1 per t)
            const int sv = (t + 1) / 7;
            if (sv >= 1 && 7 * sv >= t - 4 && 7 * sv <= t + 1) {
                const int start = 7 * sv - 1;
                const int len = t - start + 1;          // 1..6 by construction
                float s = r[start % 7];
#pragma unroll
                for (int k = 1; k < len; ++k) s = __fadd_rn(s, r[(start + k) % 7]);
                wsp[(size_t)(127 + (sv - 1) * 6 + (len - 1)) * BD] = s;
            }
        }
    }
}

// ---------------------------------------------------------------------------
// kA1 (r6 version, verified): 64-b tile, lane = (h-quad q, b-octet).
// CUR1 bit-identical (ascending-d single-acc fma chain). UNCHANGED.
// ---------------------------------------------------------------------------
__global__ __launch_bounds__(256) void kA_wincur(const float* __restrict__ WS,
                                                 const float* __restrict__ WinT,
                                                 float* __restrict__ CUR1) {
    __shared__ float xs[D_INPUT * 64];                  // 24 KB, xs[d*64 + (bq^(d&24))]
    __shared__ float wq[D_INPUT * H_DIM];               // 48 KB, pair-split per row
    const int widx = blockIdx.x;
    const int b0   = blockIdx.y * 64;
    const int tid  = threadIdx.x;

    {
        const float2* WinT2 = (const float2*)WinT;
        for (int e2 = tid; e2 < D_INPUT * 64; e2 += 256) {
            const int p = e2 & 63, d = e2 >> 6;
            *(float2*)&wq[d * 128 + ((p & 1) << 6) + ((p >> 1) << 1)] = WinT2[e2];
        }
    }
    for (int e = tid; e < D_INPUT * 64; e += 256) {
        const int d = e % 96, bq = e / 96;
        xs[d * 64 + (bq ^ (d & 24))] =
            WS[(size_t)widx * BD + (size_t)(b0 + bq) * 96 + d];
    }
    __syncthreads();

    const int q  = tid & 31;                            // h-quad (4 h's)
    const int g  = (tid >> 5) & 1;
    const int w  = tid >> 6;
    const int ob = (w << 1) | g;                        // b-octet 0..7

    float acc[8][4];
#pragma unroll
    for (int r = 0; r < 8; ++r)
#pragma unroll
        for (int hh = 0; hh < 4; ++hh) acc[r][hh] = 0.f;

#pragma unroll 4
    for (int d = 0; d < D_INPUT; ++d) {
        const float2 wp0 = *(const float2*)&wq[d * 128 + 2 * q];       // h=4q,4q+1
        const float2 wp1 = *(const float2*)&wq[d * 128 + 64 + 2 * q];  // h=4q+2,4q+3
        const int xb = d * 64 + ((ob * 8) ^ (d & 24));
        const float4 xv0 = *(const float4*)&xs[xb];
        const float4 xv1 = *(const float4*)&xs[xb + 4];
        const float xv[8] = {xv0.x,xv0.y,xv0.z,xv0.w, xv1.x,xv1.y,xv1.z,xv1.w};
#pragma unroll
        for (int r = 0; r < 8; ++r) {
            acc[r][0] = __fmaf_rn(xv[r], wp0.x, acc[r][0]);
            acc[r][1] = __fmaf_rn(xv[r], wp0.y, acc[r][1]);
            acc[r][2] = __fmaf_rn(xv[r], wp1.x, acc[r][2]);
            acc[r][3] = __fmaf_rn(xv[r], wp1.y, acc[r][3]);
        }
    }
    float* op = CUR1 + ((size_t)widx * BATCH + b0 + ob * 8) * H_DIM + 4 * q;
#pragma unroll
    for (int r = 0; r < 8; ++r) {
        float4 o; o.x = acc[r][0]; o.y = acc[r][1]; o.z = acc[r][2]; o.w = acc[r][3];
        *(float4*)(op + (size_t)r * H_DIM) = o;
    }
}

// ---------------------------------------------------------------------------
// kB (round-11 = r5 VERBATIM, the best verified no-spill kB: 550 µs).
// 16 (t,b) pairs per wave; cur2 lane = (g = b-subgroup of 8, q = i-quad).
// Per j per lane: 4 broadcast b128 spike reads of the lane's own 8-b strip,
// 2 coalesced float4 weights from L2-resident Wh0Q, 64 fma (raw f32 spikes).
// mem1 phase / publish swizzle / c1 prefetch / relaxed Wout tail as verified.
// Ledger: r5 550 < r9 585 < r8 597 < r0 634 < r10 627 — recombining r5-kB
// with the r6 kA-path (remainder 279 -> ~227 µs, independently verified).
// ---------------------------------------------------------------------------
__global__ __launch_bounds__(512, 2) void kB_snn(const float* __restrict__ CUR1,
                                                 const float* __restrict__ Wh0Q,
                                                 const float* __restrict__ Wout,
                                                 const float* __restrict__ vxp,
                                                 const float* __restrict__ vyp,
                                                 float* __restrict__ out) {
    __shared__ float sf[8][64 * 32];                    // 64 KB, per-wave spike floats
    const int tid = threadIdx.x;

    const int w = tid >> 6, lane = tid & 63;
    const int t  = blockIdx.y;
    const int i0 = lane << 1;                           // mem1 h-pair (unchanged role)
    const int g  = lane >> 5;                           // cur2: b-subgroup (8 b's)
    const int q  = lane & 31;                           // cur2: i-quad
    const int iq = q << 2;
    float* sfw = sf[w];
    const int lbase = lane * 32;                        // publish strip (h-pair = lane)
    const float4 wex4 = *(const float4*)&Wout[iq];          // out0, i = iq..iq+3
    const float4 wey4 = *(const float4*)&Wout[H_DIM + iq];  // out1
    const float vx = vxp[0], vy = vyp[0];
    const int b0 = (blockIdx.x << 7) + (w << 4);        // 16 consecutive b per wave

    float m1a[16], m1b[16], c1a[16], c1b[16];
    bool  s1a[16], s1b[16];
    float m2[8][4], po0[8], po1[8];
    bool  s2[8][4];
#pragma unroll
    for (int k = 0; k < 16; ++k) {
        m1a[k]=0.f; m1b[k]=0.f; s1a[k]=false; s1b[k]=false;
    }
#pragma unroll
    for (int b = 0; b < 8; ++b) {
        po0[b]=0.f; po1[b]=0.f;
#pragma unroll
        for (int r = 0; r < 4; ++r) { m2[b][r]=0.f; s2[b][r]=false; }
    }

    // load cur1 for s = 0
    {
        const int wi = widx_for(t, 0);
#pragma unroll
        for (int k = 0; k < 16; ++k) {
            c1a[k] = 0.f; c1b[k] = 0.f;
            if (wi >= 0) {
                const float2 v = *(const float2*)
                    &CUR1[((size_t)wi * BATCH + b0 + k) * H_DIM + i0];
                c1a[k] = v.x; c1b[k] = v.y;
            }
        }
    }

#pragma unroll 1
    for (int s = 0; s < 7; ++s) {
        // ---- mem1 update + spike floats (exact), publish to sf -------------
        float sev[16], sov[16];
#pragma unroll
        for (int k = 0; k < 16; ++k) {
            m1a[k] = s1a[k] ? 0.f : __fadd_rn(__fmul_rn(0.9f, m1a[k]), c1a[k]);
            m1b[k] = s1b[k] ? 0.f : __fadd_rn(__fmul_rn(0.9f, m1b[k]), c1b[k]);
            s1a[k] = m1a[k] > 0.5f; s1b[k] = m1b[k] > 0.5f;
            sev[k] = s1a[k] ? 1.0f : 0.0f;
            sov[k] = s1b[k] ? 1.0f : 0.0f;
        }
        // chunks 0..3 = se[0..15], 4..7 = so[0..15]; chunk swizzled by lane&7
#pragma unroll
        for (int c = 0; c < 4; ++c) {
            float4 v;
            v.x = sev[c*4]; v.y = sev[c*4+1]; v.z = sev[c*4+2]; v.w = sev[c*4+3];
            *(float4*)&sfw[lbase + ((c     ^ (lane & 7)) << 2)] = v;
            v.x = sov[c*4]; v.y = sov[c*4+1]; v.z = sov[c*4+2]; v.w = sov[c*4+3];
            *(float4*)&sfw[lbase + (((c+4) ^ (lane & 7)) << 2)] = v;
        }

        // ---- prefetch next step's cur1 into the now-dead c1 registers ------
        const int win = (s < 6) ? widx_for(t, s + 1) : -1;
#pragma unroll
        for (int k = 0; k < 16; ++k) {
            c1a[k] = 0.f; c1b[k] = 0.f;
            if (win >= 0) {
                const float2 v = *(const float2*)
                    &CUR1[((size_t)win * BATCH + b0 + k) * H_DIM + i0];
                c1a[k] = v.x; c1b[k] = v.y;
            }
        }

        // ---- dense cur2: ascending h; 4 broadcast b128 + 2 float4 VMEM / j -
        float c2[8][4];
#pragma unroll
        for (int b = 0; b < 8; ++b)
#pragma unroll
            for (int r = 0; r < 4; ++r) c2[b][r] = 0.f;

#pragma unroll 8
        for (int j = 0; j < 64; ++j) {
            const float4 we4 = *(const float4*)&Wh0Q[((size_t)(j * 32 + q)) * 8];
            const float4 wo4 = *(const float4*)&Wh0Q[((size_t)(j * 32 + q)) * 8 + 4];
            const int jb = j * 32, jx = (j & 7) << 2;
            // this lane's 8-b strip: se chunks 2g,2g+1; so chunks 2g+4,2g+5
            const float4 E0 = *(const float4*)&sfw[jb + (((2*g    ) << 2) ^ jx)];
            const float4 E1 = *(const float4*)&sfw[jb + (((2*g + 1) << 2) ^ jx)];
            const float4 O0 = *(const float4*)&sfw[jb + (((2*g + 4) << 2) ^ jx)];
            const float4 O1 = *(const float4*)&sfw[jb + (((2*g + 5) << 2) ^ jx)];
            const float sevj[8] = {E0.x,E0.y,E0.z,E0.w, E1.x,E1.y,E1.z,E1.w};
            const float sovj[8] = {O0.x,O0.y,O0.z,O0.w, O1.x,O1.y,O1.z,O1.w};
            const float wev[4] = {we4.x, we4.y, we4.z, we4.w};
            const float wov[4] = {wo4.x, wo4.y, wo4.z, wo4.w};
#pragma unroll
            for (int b = 0; b < 8; ++b) {
#pragma unroll
                for (int r = 0; r < 4; ++r) {
                    c2[b][r] = __fmaf_rn(sevj[b], wev[r], c2[b][r]);   // h = 2j
                    c2[b][r] = __fmaf_rn(sovj[b], wov[r], c2[b][r]);   // h = 2j+1
                }
            }
        }

        // ---- mem2 + spikes (exact) and linear output tail (relaxed) --------
#pragma unroll
        for (int b = 0; b < 8; ++b) {
            float p0 = 0.f, p1 = 0.f;
#pragma unroll
            for (int r = 0; r < 4; ++r) {
                m2[b][r] = s2[b][r] ? 0.f
                         : __fadd_rn(__fmul_rn(0.9f, m2[b][r]), c2[b][r]);
                s2[b][r] = m2[b][r] > 0.5f;
                p0 += s2[b][r] ? ((const float*)&wex4)[r] : 0.f;
                p1 += s2[b][r] ? ((const float*)&wey4)[r] : 0.f;
            }
            po0[b] = __fmaf_rn(0.9f, po0[b], p0);       // mem_out linear: order-safe
            po1[b] = __fmaf_rn(0.9f, po1[b], p1);
        }
    }

    // ---- reduce per-lane output partials over the 32-lane i-groups ----------
#pragma unroll
    for (int b = 0; b < 8; ++b) {
        float r0 = po0[b], r1 = po1[b];
#pragma unroll
        for (int off = 16; off > 0; off >>= 1) {
            r0 += __shfl_xor(r0, off);
            r1 += __shfl_xor(r1, off);
        }
        if (q == 0) {
            float2 o;
            o.x = __fmul_rn(r0, vx);
            o.y = __fmul_rn(r1, vy);
            *(float2*)(out + ((size_t)t * BATCH + b0 + g * 8 + b) * 2) = o;
        }
    }
}

// ---------------------------------------------------------------------------
extern "C" void kernel_launch(void* const* d_in, const int* in_sizes, int n_in,
                              void* d_out, int out_size, void* d_ws, size_t ws_size,
                              hipStream_t stream) {
    const float* x    = (const float*)d_in[0];   // (128,1024,96)
    const float* Win  = (const float*)d_in[1];   // (128,96)
    const float* Wh0  = (const float*)d_in[2];   // (128,128)
    const float* Wout = (const float*)d_in[3];   // (2,128)
    const float* vx   = (const float*)d_in[4];   // (1,)
    const float* vy   = (const float*)d_in[5];   // (1,)
    float* out  = (float*)d_out;                 // (128,1024,2)

    // workspace: CUR1 (85.5 MB) | WS (64.1 MB) | WinT (48 KB) | Wh0Q (64 KB)
    float* CUR1 = (float*)d_ws;
    float* WS   = CUR1 + (size_t)NWIN * BATCH * H_DIM;
    float* WinT = WS   + (size_t)NWIN * BATCH * D_INPUT;
    float* Wh0Q = WinT + (size_t)D_INPUT * H_DIM;

    kT_wint   <<<dim3(112),                  dim3(256), 0, stream>>>(Win, Wh0, WinT, Wh0Q);
    kA0_winsum<<<dim3(BD / 256),             dim3(256), 0, stream>>>(x, WS);
    kA_wincur <<<dim3(NWIN, BATCH / 64),     dim3(256), 0, stream>>>(WS, WinT, CUR1);
    kB_snn    <<<dim3(BATCH / 128, T_STEPS), dim3(512), 0, stream>>>(CUR1, Wh0Q, Wout, vx, vy, out);
}

// Round 12
// 769.301 us; speedup vs baseline: 1.1058x; 1.0119x over previous
//
#include <hip/hip_runtime.h>
#include <cstdint>

#define T_STEPS 128
#define BATCH   1024
#define D_INPUT 96
#define H_DIM   128
#define NWIN    163   // 121 full 7-frame windows + 6 prefix partials + 36 clipped partials
#define BD      (BATCH * D_INPUT)   // 98304 floats per time frame

// (t, s) -> widx, or -1 when the reference window is empty (cur1 == +0)
__device__ __forceinline__ int widx_for(int t, int s) {
    if (t >= 49) return t - 49 + 7 * s;                 // slide regime: full windows
    if (s == 0)  return 121 + min(5, t);                // [0, min(5,t)]
    const int st = 7 * s - 1;
    if (t < st) return -1;
    const int len = min(7, t - st + 1);
    return (len == 7) ? st : (127 + (s - 1) * 6 + (len - 1));
}

// ---------------------------------------------------------------------------
// kT (r5 version): one-shot weight reshapes.
//   blocks 0..47  : Win (128x96)  -> WinT (96x128)
//   blocks 48..111: Wh0 (128x128) -> Wh0Q packed per (j, i-quad q):
//     Wh0Q[((j*32+q)*2+p)*4 + r] = Wh0[(4q+r)*128 + (2j+p)]
// ---------------------------------------------------------------------------
__global__ __launch_bounds__(256) void kT_wint(const float* __restrict__ Win,
                                               const float* __restrict__ Wh0,
                                               float* __restrict__ WinT,
                                               float* __restrict__ Wh0Q) {
    const int tid = threadIdx.x;
    if (blockIdx.x < 48) {
        const int e = blockIdx.x * 256 + tid;           // < 128*96
        const int h = e / D_INPUT, d = e % D_INPUT;
        WinT[d * H_DIM + h] = Win[e];
    } else {
        const int e = (blockIdx.x - 48) * 256 + tid;    // < 64*32*2*4 = 16384
        const int r = e & 3, p = (e >> 2) & 1, q = (e >> 3) & 31, j = e >> 8;
        Wh0Q[e] = Wh0[(4 * q + r) * H_DIM + (2 * j + p)];
    }
}

// ---------------------------------------------------------------------------
// kA0: one streaming pass over x. Thread <-> (b,d); 7-frame ring in registers
// (t-loop fully unrolled -> all ring indices compile-time -> no scratch).
// Emits every window sum with the EXACT ascending-frame __fadd_rn chain.
// UNCHANGED.
// ---------------------------------------------------------------------------
__global__ __launch_bounds__(256) void kA0_winsum(const float* __restrict__ x,
                                                  float* __restrict__ WS) {
    const int flat = blockIdx.x * 256 + threadIdx.x;    // b*96 + d
    float* wsp = WS + flat;
    float r[7];
#pragma unroll
    for (int t = 0; t < T_STEPS; ++t) {
        r[t % 7] = x[(size_t)t * BD + flat];
        if (t <= 5) {                                   // s0 prefix, len = t+1
            float s = r[0];
#pragma unroll
            for (int k = 1; k <= t; ++k) s = __fadd_rn(s, r[k % 7]);
            wsp[(size_t)(121 + t) * BD] = s;
        }
        if (t >= 6 && t <= 126) {                       // full window w = t-6
            const int w = t - 6;
            float s = r[w % 7];
#pragma unroll
            for (int k = 1; k < 7; ++k) s = __fadd_rn(s, r[(w + k) % 7]);
            wsp[(size_t)w * BD] = s;
        }
        if (t >= 6 && t <= 46) {                        // grow partial (<=1 per t)
            const int sv = (t + 1) / 7;
            if (sv >= 1 && 7 * sv >= t - 4 && 7 * sv <= t + 1) {
                const int start = 7 * sv - 1;
                const int len = t - start + 1;          // 1..6 by construction
                float s = r[start % 7];
#pragma unroll
                for (int k = 1; k < len; ++k) s = __fadd_rn(s, r[(start + k) % 7]);
                wsp[(size_t)(127 + (sv - 1) * 6 + (len - 1)) * BD] = s;
            }
        }
    }
}

// ---------------------------------------------------------------------------
// kA1 (round-12): rebuilt in the r5-kB mold — the proven low-LDS recipe.
// Old (r6) per wave per d: 2 b64 + 2 b128 LDS (~40 pipe-cyc) per 32 fma
// (16 cyc VALU/CU) -> LDS-bound 2.5:1, ~7x above kA1's 26 µs fma floor.
// New: lane = (hq = h-quad, g = b-octet half); per d per lane:
//   1 coalesced float4 VMEM  wv = WinT[d*128 + 4hq]   (48 KB L1/L2-hot
//      table; all 4 waves share each 512-B row -> strong temporal locality)
//   2 broadcast b128 LDS     xv = 8 b window sums (r6's verified swizzle)
//   32 fma (acc 8b x 4h)
// -> LDS:VALU = 24N:16N, and wq leaves LDS: 72 -> 24 KB (up to 6 blocks/CU).
// Bit-exact: same ascending-d single-acc fma chain per (b,h), identical
// operand values (WS via same staging; Win via WinT directly instead of an
// LDS copy of WinT) -> CUR1 bit-identical. __launch_bounds__(256,4): VGPR
// cap 128, expected natural ~80 (spill-safe margin, r7/r9 lesson).
// ---------------------------------------------------------------------------
__global__ __launch_bounds__(256, 4) void kA_wincur(const float* __restrict__ WS,
                                                    const float* __restrict__ WinT,
                                                    float* __restrict__ CUR1) {
    __shared__ float xs[D_INPUT * 64];                  // 24 KB, xs[d*64 + (bq^(d&24))]
    const int widx = blockIdx.x;
    const int b0   = blockIdx.y * 64;
    const int tid  = threadIdx.x;

    // stage window sums (coalesced global read; 8-way swizzled LDS write)
    for (int e = tid; e < D_INPUT * 64; e += 256) {
        const int d = e % 96, bq = e / 96;
        xs[d * 64 + (bq ^ (d & 24))] =
            WS[(size_t)widx * BD + (size_t)(b0 + bq) * 96 + d];
    }
    __syncthreads();

    const int w    = tid >> 6;                          // wave 0..3
    const int lane = tid & 63;
    const int hq   = lane & 31;                         // h-quad: h = 4hq..4hq+3
    const int g    = lane >> 5;                         // b-octet half 0..1
    const int bb   = (w << 4) + (g << 3);               // b offset in block: 8 b's

    float acc[8][4];
#pragma unroll
    for (int r = 0; r < 8; ++r)
#pragma unroll
        for (int hh = 0; hh < 4; ++hh) acc[r][hh] = 0.f;

#pragma unroll 8
    for (int d = 0; d < D_INPUT; ++d) {
        const float4 wv = *(const float4*)&WinT[d * H_DIM + 4 * hq];  // coalesced VMEM
        const int xb = d * 64 + (bb ^ (d & 24));        // d&24 const per 8-group
        const float4 xv0 = *(const float4*)&xs[xb];     // broadcast b128
        const float4 xv1 = *(const float4*)&xs[xb + 4];
        const float xv[8] = {xv0.x,xv0.y,xv0.z,xv0.w, xv1.x,xv1.y,xv1.z,xv1.w};
#pragma unroll
        for (int r = 0; r < 8; ++r) {
            acc[r][0] = __fmaf_rn(xv[r], wv.x, acc[r][0]);
            acc[r][1] = __fmaf_rn(xv[r], wv.y, acc[r][1]);
            acc[r][2] = __fmaf_rn(xv[r], wv.z, acc[r][2]);
            acc[r][3] = __fmaf_rn(xv[r], wv.w, acc[r][3]);
        }
    }
    float* op = CUR1 + ((size_t)widx * BATCH + b0 + bb) * H_DIM + 4 * hq;
#pragma unroll
    for (int r = 0; r < 8; ++r) {
        float4 o; o.x = acc[r][0]; o.y = acc[r][1]; o.z = acc[r][2]; o.w = acc[r][3];
        *(float4*)(op + (size_t)r * H_DIM) = o;
    }
}

// ---------------------------------------------------------------------------
// kB (r5/r11 VERBATIM — best verified: 548 µs, no spill, 0 conflicts).
// 16 (t,b) pairs per wave; cur2 lane = (g = b-subgroup of 8, q = i-quad).
// Per j per lane: 4 broadcast b128 spike reads, 2 coalesced float4 weights
// from L2-resident Wh0Q, 64 fma. UNCHANGED this round.
// ---------------------------------------------------------------------------
__global__ __launch_bounds__(512, 2) void kB_snn(const float* __restrict__ CUR1,
                                                 const float* __restrict__ Wh0Q,
                                                 const float* __restrict__ Wout,
                                                 const float* __restrict__ vxp,
                                                 const float* __restrict__ vyp,
                                                 float* __restrict__ out) {
    __shared__ float sf[8][64 * 32];                    // 64 KB, per-wave spike floats
    const int tid = threadIdx.x;

    const int w = tid >> 6, lane = tid & 63;
    const int t  = blockIdx.y;
    const int i0 = lane << 1;                           // mem1 h-pair (unchanged role)
    const int g  = lane >> 5;                           // cur2: b-subgroup (8 b's)
    const int q  = lane & 31;                           // cur2: i-quad
    const int iq = q << 2;
    float* sfw = sf[w];
    const int lbase = lane * 32;                        // publish strip (h-pair = lane)
    const float4 wex4 = *(const float4*)&Wout[iq];          // out0, i = iq..iq+3
    const float4 wey4 = *(const float4*)&Wout[H_DIM + iq];  // out1
    const float vx = vxp[0], vy = vyp[0];
    const int b0 = (blockIdx.x << 7) + (w << 4);        // 16 consecutive b per wave

    float m1a[16], m1b[16], c1a[16], c1b[16];
    bool  s1a[16], s1b[16];
    float m2[8][4], po0[8], po1[8];
    bool  s2[8][4];
#pragma unroll
    for (int k = 0; k < 16; ++k) {
        m1a[k]=0.f; m1b[k]=0.f; s1a[k]=false; s1b[k]=false;
    }
#pragma unroll
    for (int b = 0; b < 8; ++b) {
        po0[b]=0.f; po1[b]=0.f;
#pragma unroll
        for (int r = 0; r < 4; ++r) { m2[b][r]=0.f; s2[b][r]=false; }
    }

    // load cur1 for s = 0
    {
        const int wi = widx_for(t, 0);
#pragma unroll
        for (int k = 0; k < 16; ++k) {
            c1a[k] = 0.f; c1b[k] = 0.f;
            if (wi >= 0) {
                const float2 v = *(const float2*)
                    &CUR1[((size_t)wi * BATCH + b0 + k) * H_DIM + i0];
                c1a[k] = v.x; c1b[k] = v.y;
            }
        }
    }

#pragma unroll 1
    for (int s = 0; s < 7; ++s) {
        // ---- mem1 update + spike floats (exact), publish to sf -------------
        float sev[16], sov[16];
#pragma unroll
        for (int k = 0; k < 16; ++k) {
            m1a[k] = s1a[k] ? 0.f : __fadd_rn(__fmul_rn(0.9f, m1a[k]), c1a[k]);
            m1b[k] = s1b[k] ? 0.f : __fadd_rn(__fmul_rn(0.9f, m1b[k]), c1b[k]);
            s1a[k] = m1a[k] > 0.5f; s1b[k] = m1b[k] > 0.5f;
            sev[k] = s1a[k] ? 1.0f : 0.0f;
            sov[k] = s1b[k] ? 1.0f : 0.0f;
        }
        // chunks 0..3 = se[0..15], 4..7 = so[0..15]; chunk swizzled by lane&7
#pragma unroll
        for (int c = 0; c < 4; ++c) {
            float4 v;
            v.x = sev[c*4]; v.y = sev[c*4+1]; v.z = sev[c*4+2]; v.w = sev[c*4+3];
            *(float4*)&sfw[lbase + ((c     ^ (lane & 7)) << 2)] = v;
            v.x = sov[c*4]; v.y = sov[c*4+1]; v.z = sov[c*4+2]; v.w = sov[c*4+3];
            *(float4*)&sfw[lbase + (((c+4) ^ (lane & 7)) << 2)] = v;
        }

        // ---- prefetch next step's cur1 into the now-dead c1 registers ------
        const int win = (s < 6) ? widx_for(t, s + 1) : -1;
#pragma unroll
        for (int k = 0; k < 16; ++k) {
            c1a[k] = 0.f; c1b[k] = 0.f;
            if (win >= 0) {
                const float2 v = *(const float2*)
                    &CUR1[((size_t)win * BATCH + b0 + k) * H_DIM + i0];
                c1a[k] = v.x; c1b[k] = v.y;
            }
        }

        // ---- dense cur2: ascending h; 4 broadcast b128 + 2 float4 VMEM / j -
        float c2[8][4];
#pragma unroll
        for (int b = 0; b < 8; ++b)
#pragma unroll
            for (int r = 0; r < 4; ++r) c2[b][r] = 0.f;

#pragma unroll 8
        for (int j = 0; j < 64; ++j) {
            const float4 we4 = *(const float4*)&Wh0Q[((size_t)(j * 32 + q)) * 8];
            const float4 wo4 = *(const float4*)&Wh0Q[((size_t)(j * 32 + q)) * 8 + 4];
            const int jb = j * 32, jx = (j & 7) << 2;
            // this lane's 8-b strip: se chunks 2g,2g+1; so chunks 2g+4,2g+5
            const float4 E0 = *(const float4*)&sfw[jb + (((2*g    ) << 2) ^ jx)];
            const float4 E1 = *(const float4*)&sfw[jb + (((2*g + 1) << 2) ^ jx)];
            const float4 O0 = *(const float4*)&sfw[jb + (((2*g + 4) << 2) ^ jx)];
            const float4 O1 = *(const float4*)&sfw[jb + (((2*g + 5) << 2) ^ jx)];
            const float sevj[8] = {E0.x,E0.y,E0.z,E0.w, E1.x,E1.y,E1.z,E1.w};
            const float sovj[8] = {O0.x,O0.y,O0.z,O0.w, O1.x,O1.y,O1.z,O1.w};
            const float wev[4] = {we4.x, we4.y, we4.z, we4.w};
            const float wov[4] = {wo4.x, wo4.y, wo4.z, wo4.w};
#pragma unroll
            for (int b = 0; b < 8; ++b) {
#pragma unroll
                for (int r = 0; r < 4; ++r) {
                    c2[b][r] = __fmaf_rn(sevj[b], wev[r], c2[b][r]);   // h = 2j
                    c2[b][r] = __fmaf_rn(sovj[b], wov[r], c2[b][r]);   // h = 2j+1
                }
            }
        }

        // ---- mem2 + spikes (exact) and linear output tail (relaxed) --------
#pragma unroll
        for (int b = 0; b < 8; ++b) {
            float p0 = 0.f, p1 = 0.f;
#pragma unroll
            for (int r = 0; r < 4; ++r) {
                m2[b][r] = s2[b][r] ? 0.f
                         : __fadd_rn(__fmul_rn(0.9f, m2[b][r]), c2[b][r]);
                s2[b][r] = m2[b][r] > 0.5f;
                p0 += s2[b][r] ? ((const float*)&wex4)[r] : 0.f;
                p1 += s2[b][r] ? ((const float*)&wey4)[r] : 0.f;
            }
            po0[b] = __fmaf_rn(0.9f, po0[b], p0);       // mem_out linear: order-safe
            po1[b] = __fmaf_rn(0.9f, po1[b], p1);
        }
    }

    // ---- reduce per-lane output partials over the 32-lane i-groups ----------
#pragma unroll
    for (int b = 0; b < 8; ++b) {
        float r0 = po0[b], r1 = po1[b];
#pragma unroll
        for (int off = 16; off > 0; off >>= 1) {
            r0 += __shfl_xor(r0, off);
            r1 += __shfl_xor(r1, off);
        }
        if (q == 0) {
            float2 o;
            o.x = __fmul_rn(r0, vx);
            o.y = __fmul_rn(r1, vy);
            *(float2*)(out + ((size_t)t * BATCH + b0 + g * 8 + b) * 2) = o;
        }
    }
}

// ---------------------------------------------------------------------------
extern "C" void kernel_launch(void* const* d_in, const int* in_sizes, int n_in,
                              void* d_out, int out_size, void* d_ws, size_t ws_size,
                              hipStream_t stream) {
    const float* x    = (const float*)d_in[0];   // (128,1024,96)
    const float* Win  = (const float*)d_in[1];   // (128,96)
    const float* Wh0  = (const float*)d_in[2];   // (128,128)
    const float* Wout = (const float*)d_in[3];   // (2,128)
    const float* vx   = (const float*)d_in[4];   // (1,)
    const float* vy   = (const float*)d_in[5];   // (1,)
    float* out  = (float*)d_out;                 // (128,1024,2)

    // workspace: CUR1 (85.5 MB) | WS (64.1 MB) | WinT (48 KB) | Wh0Q (64 KB)
    float* CUR1 = (float*)d_ws;
    float* WS   = CUR1 + (size_t)NWIN * BATCH * H_DIM;
    float* WinT = WS   + (size_t)NWIN * BATCH * D_INPUT;
    float* Wh0Q = WinT + (size_t)D_INPUT * H_DIM;

    kT_wint   <<<dim3(112),                  dim3(256), 0, stream>>>(Win, Wh0, WinT, Wh0Q);
    kA0_winsum<<<dim3(BD / 256),             dim3(256), 0, stream>>>(x, WS);
    kA_wincur <<<dim3(NWIN, BATCH / 64),     dim3(256), 0, stream>>>(WS, WinT, CUR1);
    kB_snn    <<<dim3(BATCH / 128, T_STEPS), dim3(512), 0, stream>>>(CUR1, Wh0Q, Wout, vx, vy, out);
}

// Round 13
// 756.565 us; speedup vs baseline: 1.1244x; 1.0168x over previous
//
#include <hip/hip_runtime.h>
#include <cstdint>

#define T_STEPS 128
#define BATCH   1024
#define D_INPUT 96
#define H_DIM   128
#define NWIN    163   // 121 full 7-frame windows + 6 prefix partials + 36 clipped partials
#define BD      (BATCH * D_INPUT)   // 98304 floats per time frame

// (t, s) -> widx, or -1 when the reference window is empty (cur1 == +0)
__device__ __forceinline__ int widx_for(int t, int s) {
    if (t >= 49) return t - 49 + 7 * s;                 // slide regime: full windows
    if (s == 0)  return 121 + min(5, t);                // [0, min(5,t)]
    const int st = 7 * s - 1;
    if (t < st) return -1;
    const int len = min(7, t - st + 1);
    return (len == 7) ? st : (127 + (s - 1) * 6 + (len - 1));
}

// ---------------------------------------------------------------------------
// kT (r5 version): one-shot weight reshapes.
//   blocks 0..47  : Win (128x96)  -> WinT (96x128)
//   blocks 48..111: Wh0 (128x128) -> Wh0Q packed per (j, i-quad q):
//     Wh0Q[((j*32+q)*2+p)*4 + r] = Wh0[(4q+r)*128 + (2j+p)]
// ---------------------------------------------------------------------------
__global__ __launch_bounds__(256) void kT_wint(const float* __restrict__ Win,
                                               const float* __restrict__ Wh0,
                                               float* __restrict__ WinT,
                                               float* __restrict__ Wh0Q) {
    const int tid = threadIdx.x;
    if (blockIdx.x < 48) {
        const int e = blockIdx.x * 256 + tid;           // < 128*96
        const int h = e / D_INPUT, d = e % D_INPUT;
        WinT[d * H_DIM + h] = Win[e];
    } else {
        const int e = (blockIdx.x - 48) * 256 + tid;    // < 64*32*2*4 = 16384
        const int r = e & 3, p = (e >> 2) & 1, q = (e >> 3) & 31, j = e >> 8;
        Wh0Q[e] = Wh0[(4 * q + r) * H_DIM + (2 * j + p)];
    }
}

// ---------------------------------------------------------------------------
// kA0: one streaming pass over x. Thread <-> (b,d); 7-frame ring in registers
// (t-loop fully unrolled -> all ring indices compile-time -> no scratch).
// Emits every window sum with the EXACT ascending-frame __fadd_rn chain.
// UNCHANGED.
// ---------------------------------------------------------------------------
__global__ __launch_bounds__(256) void kA0_winsum(const float* __restrict__ x,
                                                  float* __restrict__ WS) {
    const int flat = blockIdx.x * 256 + threadIdx.x;    // b*96 + d
    float* wsp = WS + flat;
    float r[7];
#pragma unroll
    for (int t = 0; t < T_STEPS; ++t) {
        r[t % 7] = x[(size_t)t * BD + flat];
        if (t <= 5) {                                   // s0 prefix, len = t+1
            float s = r[0];
#pragma unroll
            for (int k = 1; k <= t; ++k) s = __fadd_rn(s, r[k % 7]);
            wsp[(size_t)(121 + t) * BD] = s;
        }
        if (t >= 6 && t <= 126) {                       // full window w = t-6
            const int w = t - 6;
            float s = r[w % 7];
#pragma unroll
            for (int k = 1; k < 7; ++k) s = __fadd_rn(s, r[(w + k) % 7]);
            wsp[(size_t)w * BD] = s;
        }
        if (t >= 6 && t <= 46) {                        // grow partial (<=1 per t)
            const int sv = (t + 1) / 7;
            if (sv >= 1 && 7 * sv >= t - 4 && 7 * sv <= t + 1) {
                const int start = 7 * sv - 1;
                const int len = t - start + 1;          // 1..6 by construction
                float s = r[start % 7];
#pragma unroll
                for (int k = 1; k < len; ++k) s = __fadd_rn(s, r[(start + k) % 7]);
                wsp[(size_t)(127 + (sv - 1) * 6 + (len - 1)) * BD] = s;
            }
        }
    }
}

// ---------------------------------------------------------------------------
// kA1 (r12 version, verified): lane = (hq = h-quad, g = b-octet half).
// Per d: 1 coalesced float4 VMEM (WinT) + 2 broadcast b128 (xs) -> 32 fma.
// CUR1 bit-identical (ascending-d single-acc fma chain). UNCHANGED.
// ---------------------------------------------------------------------------
__global__ __launch_bounds__(256, 4) void kA_wincur(const float* __restrict__ WS,
                                                    const float* __restrict__ WinT,
                                                    float* __restrict__ CUR1) {
    __shared__ float xs[D_INPUT * 64];                  // 24 KB, xs[d*64 + (bq^(d&24))]
    const int widx = blockIdx.x;
    const int b0   = blockIdx.y * 64;
    const int tid  = threadIdx.x;

    // stage window sums (coalesced global read; 8-way swizzled LDS write)
    for (int e = tid; e < D_INPUT * 64; e += 256) {
        const int d = e % 96, bq = e / 96;
        xs[d * 64 + (bq ^ (d & 24))] =
            WS[(size_t)widx * BD + (size_t)(b0 + bq) * 96 + d];
    }
    __syncthreads();

    const int w    = tid >> 6;                          // wave 0..3
    const int lane = tid & 63;
    const int hq   = lane & 31;                         // h-quad: h = 4hq..4hq+3
    const int g    = lane >> 5;                         // b-octet half 0..1
    const int bb   = (w << 4) + (g << 3);               // b offset in block: 8 b's

    float acc[8][4];
#pragma unroll
    for (int r = 0; r < 8; ++r)
#pragma unroll
        for (int hh = 0; hh < 4; ++hh) acc[r][hh] = 0.f;

#pragma unroll 8
    for (int d = 0; d < D_INPUT; ++d) {
        const float4 wv = *(const float4*)&WinT[d * H_DIM + 4 * hq];  // coalesced VMEM
        const int xb = d * 64 + (bb ^ (d & 24));        // d&24 const per 8-group
        const float4 xv0 = *(const float4*)&xs[xb];     // broadcast b128
        const float4 xv1 = *(const float4*)&xs[xb + 4];
        const float xv[8] = {xv0.x,xv0.y,xv0.z,xv0.w, xv1.x,xv1.y,xv1.z,xv1.w};
#pragma unroll
        for (int r = 0; r < 8; ++r) {
            acc[r][0] = __fmaf_rn(xv[r], wv.x, acc[r][0]);
            acc[r][1] = __fmaf_rn(xv[r], wv.y, acc[r][1]);
            acc[r][2] = __fmaf_rn(xv[r], wv.z, acc[r][2]);
            acc[r][3] = __fmaf_rn(xv[r], wv.w, acc[r][3]);
        }
    }
    float* op = CUR1 + ((size_t)widx * BATCH + b0 + bb) * H_DIM + 4 * hq;
#pragma unroll
    for (int r = 0; r < 8; ++r) {
        float4 o; o.x = acc[r][0]; o.y = acc[r][1]; o.z = acc[r][2]; o.w = acc[r][3];
        *(float4*)(op + (size_t)r * H_DIM) = o;
    }
}

// ---------------------------------------------------------------------------
// kB (round-13): r5/r11 body VERBATIM; ONLY block granularity changes.
// Diagnosis from r12 counters: cur2 LDS-pipe demand ~287 µs, fma floor
// ~191 µs, measured 548 µs at VALUBusy 53% -> BOTH pipes ~half-idle ->
// latency/dependency-bound, needs more resident waves. Occupancy counter
// stuck at ~22% despite resources admitting 16 waves/CU; history shows
// large blocks pack poorly (r8 512thr 39%, r10 1024thr 34%, r5 512thr 22%).
// kB has NO __syncthreads and no inter-wave sharing (sf per-wave, weights
// via VMEM) -> block size is pure scheduling granularity. Shrink to 4-wave
// blocks: sf 64->32 KB, up to 5 blocks/CU by LDS, 4 by VGPR (112) -> finer
// packing. Body/fma chains/publish swizzle/prefetch bit-identical; grid x2.
// ---------------------------------------------------------------------------
__global__ __launch_bounds__(256, 2) void kB_snn(const float* __restrict__ CUR1,
                                                 const float* __restrict__ Wh0Q,
                                                 const float* __restrict__ Wout,
                                                 const float* __restrict__ vxp,
                                                 const float* __restrict__ vyp,
                                                 float* __restrict__ out) {
    __shared__ float sf[4][64 * 32];                    // 32 KB, per-wave spike floats
    const int tid = threadIdx.x;

    const int w = tid >> 6, lane = tid & 63;            // w in [0,4)
    const int t  = blockIdx.y;
    const int i0 = lane << 1;                           // mem1 h-pair (unchanged role)
    const int g  = lane >> 5;                           // cur2: b-subgroup (8 b's)
    const int q  = lane & 31;                           // cur2: i-quad
    const int iq = q << 2;
    float* sfw = sf[w];
    const int lbase = lane * 32;                        // publish strip (h-pair = lane)
    const float4 wex4 = *(const float4*)&Wout[iq];          // out0, i = iq..iq+3
    const float4 wey4 = *(const float4*)&Wout[H_DIM + iq];  // out1
    const float vx = vxp[0], vy = vyp[0];
    const int b0 = (blockIdx.x << 6) + (w << 4);        // 16 consecutive b per wave

    float m1a[16], m1b[16], c1a[16], c1b[16];
    bool  s1a[16], s1b[16];
    float m2[8][4], po0[8], po1[8];
    bool  s2[8][4];
#pragma unroll
    for (int k = 0; k < 16; ++k) {
        m1a[k]=0.f; m1b[k]=0.f; s1a[k]=false; s1b[k]=false;
    }
#pragma unroll
    for (int b = 0; b < 8; ++b) {
        po0[b]=0.f; po1[b]=0.f;
#pragma unroll
        for (int r = 0; r < 4; ++r) { m2[b][r]=0.f; s2[b][r]=false; }
    }

    // load cur1 for s = 0
    {
        const int wi = widx_for(t, 0);
#pragma unroll
        for (int k = 0; k < 16; ++k) {
            c1a[k] = 0.f; c1b[k] = 0.f;
            if (wi >= 0) {
                const float2 v = *(const float2*)
                    &CUR1[((size_t)wi * BATCH + b0 + k) * H_DIM + i0];
                c1a[k] = v.x; c1b[k] = v.y;
            }
        }
    }

#pragma unroll 1
    for (int s = 0; s < 7; ++s) {
        // ---- mem1 update + spike floats (exact), publish to sf -------------
        float sev[16], sov[16];
#pragma unroll
        for (int k = 0; k < 16; ++k) {
            m1a[k] = s1a[k] ? 0.f : __fadd_rn(__fmul_rn(0.9f, m1a[k]), c1a[k]);
            m1b[k] = s1b[k] ? 0.f : __fadd_rn(__fmul_rn(0.9f, m1b[k]), c1b[k]);
            s1a[k] = m1a[k] > 0.5f; s1b[k] = m1b[k] > 0.5f;
            sev[k] = s1a[k] ? 1.0f : 0.0f;
            sov[k] = s1b[k] ? 1.0f : 0.0f;
        }
        // chunks 0..3 = se[0..15], 4..7 = so[0..15]; chunk swizzled by lane&7
#pragma unroll
        for (int c = 0; c < 4; ++c) {
            float4 v;
            v.x = sev[c*4]; v.y = sev[c*4+1]; v.z = sev[c*4+2]; v.w = sev[c*4+3];
            *(float4*)&sfw[lbase + ((c     ^ (lane & 7)) << 2)] = v;
            v.x = sov[c*4]; v.y = sov[c*4+1]; v.z = sov[c*4+2]; v.w = sov[c*4+3];
            *(float4*)&sfw[lbase + (((c+4) ^ (lane & 7)) << 2)] = v;
        }

        // ---- prefetch next step's cur1 into the now-dead c1 registers ------
        const int win = (s < 6) ? widx_for(t, s + 1) : -1;
#pragma unroll
        for (int k = 0; k < 16; ++k) {
            c1a[k] = 0.f; c1b[k] = 0.f;
            if (win >= 0) {
                const float2 v = *(const float2*)
                    &CUR1[((size_t)win * BATCH + b0 + k) * H_DIM + i0];
                c1a[k] = v.x; c1b[k] = v.y;
            }
        }

        // ---- dense cur2: ascending h; 4 broadcast b128 + 2 float4 VMEM / j -
        float c2[8][4];
#pragma unroll
        for (int b = 0; b < 8; ++b)
#pragma unroll
            for (int r = 0; r < 4; ++r) c2[b][r] = 0.f;

#pragma unroll 8
        for (int j = 0; j < 64; ++j) {
            const float4 we4 = *(const float4*)&Wh0Q[((size_t)(j * 32 + q)) * 8];
            const float4 wo4 = *(const float4*)&Wh0Q[((size_t)(j * 32 + q)) * 8 + 4];
            const int jb = j * 32, jx = (j & 7) << 2;
            // this lane's 8-b strip: se chunks 2g,2g+1; so chunks 2g+4,2g+5
            const float4 E0 = *(const float4*)&sfw[jb + (((2*g    ) << 2) ^ jx)];
            const float4 E1 = *(const float4*)&sfw[jb + (((2*g + 1) << 2) ^ jx)];
            const float4 O0 = *(const float4*)&sfw[jb + (((2*g + 4) << 2) ^ jx)];
            const float4 O1 = *(const float4*)&sfw[jb + (((2*g + 5) << 2) ^ jx)];
            const float sevj[8] = {E0.x,E0.y,E0.z,E0.w, E1.x,E1.y,E1.z,E1.w};
            const float sovj[8] = {O0.x,O0.y,O0.z,O0.w, O1.x,O1.y,O1.z,O1.w};
            const float wev[4] = {we4.x, we4.y, we4.z, we4.w};
            const float wov[4] = {wo4.x, wo4.y, wo4.z, wo4.w};
#pragma unroll
            for (int b = 0; b < 8; ++b) {
#pragma unroll
                for (int r = 0; r < 4; ++r) {
                    c2[b][r] = __fmaf_rn(sevj[b], wev[r], c2[b][r]);   // h = 2j
                    c2[b][r] = __fmaf_rn(sovj[b], wov[r], c2[b][r]);   // h = 2j+1
                }
            }
        }

        // ---- mem2 + spikes (exact) and linear output tail (relaxed) --------
#pragma unroll
        for (int b = 0; b < 8; ++b) {
            float p0 = 0.f, p1 = 0.f;
#pragma unroll
            for (int r = 0; r < 4; ++r) {
                m2[b][r] = s2[b][r] ? 0.f
                         : __fadd_rn(__fmul_rn(0.9f, m2[b][r]), c2[b][r]);
                s2[b][r] = m2[b][r] > 0.5f;
                p0 += s2[b][r] ? ((const float*)&wex4)[r] : 0.f;
                p1 += s2[b][r] ? ((const float*)&wey4)[r] : 0.f;
            }
            po0[b] = __fmaf_rn(0.9f, po0[b], p0);       // mem_out linear: order-safe
            po1[b] = __fmaf_rn(0.9f, po1[b], p1);
        }
    }

    // ---- reduce per-lane output partials over the 32-lane i-groups ----------
#pragma unroll
    for (int b = 0; b < 8; ++b) {
        float r0 = po0[b], r1 = po1[b];
#pragma unroll
        for (int off = 16; off > 0; off >>= 1) {
            r0 += __shfl_xor(r0, off);
            r1 += __shfl_xor(r1, off);
        }
        if (q == 0) {
            float2 o;
            o.x = __fmul_rn(r0, vx);
            o.y = __fmul_rn(r1, vy);
            *(float2*)(out + ((size_t)t * BATCH + b0 + g * 8 + b) * 2) = o;
        }
    }
}

// ---------------------------------------------------------------------------
extern "C" void kernel_launch(void* const* d_in, const int* in_sizes, int n_in,
                              void* d_out, int out_size, void* d_ws, size_t ws_size,
                              hipStream_t stream) {
    const float* x    = (const float*)d_in[0];   // (128,1024,96)
    const float* Win  = (const float*)d_in[1];   // (128,96)
    const float* Wh0  = (const float*)d_in[2];   // (128,128)
    const float* Wout = (const float*)d_in[3];   // (2,128)
    const float* vx   = (const float*)d_in[4];   // (1,)
    const float* vy   = (const float*)d_in[5];   // (1,)
    float* out  = (float*)d_out;                 // (128,1024,2)

    // workspace: CUR1 (85.5 MB) | WS (64.1 MB) | WinT (48 KB) | Wh0Q (64 KB)
    float* CUR1 = (float*)d_ws;
    float* WS   = CUR1 + (size_t)NWIN * BATCH * H_DIM;
    float* WinT = WS   + (size_t)NWIN * BATCH * D_INPUT;
    float* Wh0Q = WinT + (size_t)D_INPUT * H_DIM;

    kT_wint   <<<dim3(112),                 dim3(256), 0, stream>>>(Win, Wh0, WinT, Wh0Q);
    kA0_winsum<<<dim3(BD / 256),            dim3(256), 0, stream>>>(x, WS);
    kA_wincur <<<dim3(NWIN, BATCH / 64),    dim3(256), 0, stream>>>(WS, WinT, CUR1);
    kB_snn    <<<dim3(BATCH / 64, T_STEPS), dim3(256), 0, stream>>>(CUR1, Wh0Q, Wout, vx, vy, out);
}